// Round 11
// baseline (467.434 us; speedup 1.0000x reference)
//
#include <hip/hip_runtime.h>

// SparseMinCostFlow — 2-launch: [bucket + zero + chain] then [scatter].
// N=8192, E=262144, 10 iterations, dense NxN fp32 out (256 MB).
//
// Consolidated model (r1..r10):
//  - Harness poison floor ~225us is in the timed window; budget = dur - 225.
//  - Bulk traffic: plain float4 only (sc bulk stores = 434 GB/s, r7).
//  - Cross-block exchange: sc relaxed atomics, NO fences (r2/r4 = L2
//    maintenance storms). sc LOADS are per-lane fabric transactions — keep
//    them off the hot path (r10's plain-load phase A; first-touch argument
//    makes plain loads coherent: adjg slots are written once via sc
//    write-through, read only after the stage sync by XCDs that never
//    cached them; 4KB inter-slot gaps guard against L2 next-line prefetch).
//  - One sync/stage; stage 9 synced by the dispatch boundary.
//  - Kernel-launch nodes ~10us each => fuse independent work.
//
// K1 (512 blocks x 1024 thr):
//   blocks 0..31  : chain. Prologue: ballot-compact own-col edges (col>>8 ==
//                   bid) from the full edge list into a private global
//                   bucket (LDS cursor; no global cursors, no memset).
//                   Stages 1..9: phase A plain-float4 adj load -> LDS;
//                   phase B bucket -> per-wave replicated accumulators
//                   (16 x 257 padded = conflict-free); phase C relu +
//                   sc-flush own 256-float slice; flag+poll sync (s<9).
//   blocks 32..511: zero the 256 MB output (plain float4, ~6 TB/s path).
// K2 (1024 blocks x 256): out[r*N+c] += v * adj9[r].

#define NN 8192
#define EE 262144
#define THREADS 1024
#define FBLK 32
#define TOTBLK 512
#define ZBLK (TOTBLK - FBLK)
#define SLICE 256                 // NN / FBLK cols per chain block
#define CAP 10240                 // bucket capacity (avg 8192, 23 sigma)
#define NWAVE (THREADS / 64)      // 16 waves
#define RSTR 257                  // replica stride (bank-conflict-free)
#define ASTR 9216                 // adjg slot stride: 8192 + 1024 gap floats
#define N4 ((long)NN * NN / 4)
#define MAGIC 0x5CA1AB1Eu         // != 0xAAAAAAAA poison, != 0

#define LOAD_A(p)    __hip_atomic_load((p),  __ATOMIC_RELAXED, __HIP_MEMORY_SCOPE_AGENT)
#define STORE_A(p,v) __hip_atomic_store((p), (v), __ATOMIC_RELAXED, __HIP_MEMORY_SCOPE_AGENT)

__global__ void __launch_bounds__(THREADS) fused_all(
        const float* __restrict__ values, const float* __restrict__ dem,
        const int* __restrict__ rows, const int* __restrict__ cols,
        int2* __restrict__ bkt,          // FBLK * CAP private buckets
        float* __restrict__ adjg,        // 10 * ASTR floats (slots 1..9 used)
        unsigned* __restrict__ sflags,   // 64 words per stage
        float4* __restrict__ out4) {
    __shared__ float    adjF[NN];            // 32 KB full adj vector
    __shared__ float    accR[NWAVE * RSTR];  // 16.1 KB replicated accumulators
    __shared__ float    dS[SLICE];           // 1 KB own-slice demand
    __shared__ unsigned curs;
    const int bid = blockIdx.x;
    const int tid = threadIdx.x;

    if (bid >= FBLK) {
        // ---------------- zero team: 256 MB plain float4 ----------------
        long i = (long)(bid - FBLK) * THREADS + tid;
        const long stride = (long)ZBLK * THREADS;
        const float4 z = make_float4(0.f, 0.f, 0.f, 0.f);
        for (; i < N4; i += stride) out4[i] = z;
        return;
    }

    // ---------------- chain block: owns cols [bid*256, bid*256+256) -------
    const int lane = tid & 63;
    const int wid  = tid >> 6;
    int2* mybkt = bkt + (long)bid * CAP;

    if (tid == 0) curs = 0u;
    if (tid < SLICE) dS[tid] = dem[bid * SLICE + tid];
    __syncthreads();

    // ---- prologue: ballot-compact own-col edges ----
    {
        const int4*   r4 = (const int4*)rows;
        const int4*   c4 = (const int4*)cols;
        const float4* v4 = (const float4*)values;
        for (int it = 0; it < EE / (THREADS * 4); ++it) {   // 64 iters
            int g = it * THREADS + tid;
            int4 r = r4[g]; int4 c = c4[g]; float4 v = v4[g];
            #pragma unroll
            for (int j = 0; j < 4; ++j) {
                int   rr = j == 0 ? r.x : j == 1 ? r.y : j == 2 ? r.z : r.w;
                int   cc = j == 0 ? c.x : j == 1 ? c.y : j == 2 ? c.z : c.w;
                float vv = j == 0 ? v.x : j == 1 ? v.y : j == 2 ? v.z : v.w;
                bool keep = (cc >> 8) == bid;
                unsigned long long m = __ballot(keep);
                int cnt = (int)__popcll(m);
                int base = 0;
                if (lane == 0 && cnt) base = (int)atomicAdd(&curs, (unsigned)cnt);
                base = __shfl(base, 0);
                if (keep) {
                    int off = base + (int)__popcll(m & ((1ull << lane) - 1ull));
                    if (off < CAP)
                        mybkt[off] = make_int2((rr << 8) | (cc & (SLICE - 1)),
                                               __float_as_int(vv));
                }
            }
        }
    }
    __syncthreads();
    unsigned cnt = curs;
    if (cnt > CAP) cnt = CAP;

    // ---- stages 1..9 ----
    for (int s = 1; s <= 9; ++s) {
        // phase A: adjF = adj_{s-1}; zero replicated accumulators
        if (s == 1) {
            #pragma unroll
            for (int q = 0; q < NN / THREADS; ++q) {
                int i = q * THREADS + tid;
                adjF[i] = fmaxf(-dem[i], 0.f);          // adj0 = relu(0 - d)
            }
        } else {
            const float4* src = (const float4*)(adjg + (long)(s - 1) * ASTR);
            float4* dst = (float4*)adjF;
            #pragma unroll
            for (int q = 0; q < NN / 4 / THREADS; ++q)  // 2 plain float4/thread
                dst[q * THREADS + tid] = src[q * THREADS + tid];
        }
        for (int i = tid; i < NWAVE * RSTR; i += THREADS) accR[i] = 0.f;
        __syncthreads();

        // phase B: own bucket -> per-wave accumulator (no cross-wave clash)
        float* myacc = accR + wid * RSTR;
        for (unsigned i = tid; i < cnt; i += THREADS) {
            int2 e = mybkt[i];
            float a = adjF[e.x >> 8];
            atomicAdd(&myacc[e.x & (SLICE - 1)], __int_as_float(e.y) * a);
        }
        __syncthreads();

        // phase C: reduce replicas, relu, sc-flush own slice (16 lines)
        if (tid < SLICE) {
            float sum = 0.f;
            #pragma unroll
            for (int w = 0; w < NWAVE; ++w)
                sum += accR[w * RSTR + tid];            // bank (w+tid)%32: free
            float val = fmaxf(sum - dS[tid], 0.f);
            STORE_A(&adjg[(long)s * ASTR + bid * SLICE + tid], val);
        }
        __syncthreads();               // vmcnt(0): flush at coherence point

        // one sync per stage; stage 9 synced by the dispatch boundary
        if (s < 9) {
            unsigned* fl = sflags + s * 64;
            if (tid == 0) STORE_A(&fl[bid], MAGIC);
            if (tid < 64) {
                for (;;) {
                    unsigned f = (lane < FBLK) ? LOAD_A(&fl[lane]) : MAGIC;
                    if (__all(f == MAGIC)) break;
                    __builtin_amdgcn_s_sleep(4);
                }
            }
            __syncthreads();
        }
    }
}

__global__ void __launch_bounds__(256) scatter_final(
        const float* __restrict__ values,
        const int* __restrict__ rows, const int* __restrict__ cols,
        const float* __restrict__ adj9, float* __restrict__ out) {
    int e = blockIdx.x * 256 + threadIdx.x;
    int r = rows[e];
    float a = adj9[r];                  // 32 KB table, cache-resident
    atomicAdd(&out[(long)r * NN + cols[e]], values[e] * a);
}

extern "C" void kernel_launch(void* const* d_in, const int* in_sizes, int n_in,
                              void* d_out, int out_size, void* d_ws, size_t ws_size,
                              hipStream_t stream) {
    const float* values = (const float*)d_in[0];
    const float* dem    = (const float*)d_in[1];
    const int*   rows   = (const int*)d_in[2];
    const int*   cols   = (const int*)d_in[3];
    float* out = (float*)d_out;

    // ws: buckets 2.62 MB | adjg 368 KB | sflags 2.3 KB
    int2*     bkt    = (int2*)d_ws;
    float*    adjg   = (float*)(bkt + (long)FBLK * CAP);
    unsigned* sflags = (unsigned*)(adjg + 10L * ASTR);

    fused_all<<<TOTBLK, THREADS, 0, stream>>>(
        values, dem, rows, cols, bkt, adjg, sflags, (float4*)out);

    scatter_final<<<EE / 256, 256, 0, stream>>>(
        values, rows, cols, adjg + 9L * ASTR, out);
}